// Round 7
// baseline (341.766 us; speedup 1.0000x reference)
//
#include <hip/hip_runtime.h>

#define DIMC 384
#define NTOK 1024
#define BATCH 32
#define KT12 12

using short8 = __attribute__((ext_vector_type(8))) short;
using f32x4  = __attribute__((ext_vector_type(4))) float;
using uint4_ = __attribute__((ext_vector_type(4))) unsigned int;
typedef unsigned short u16;

#define MFMA16 __builtin_amdgcn_mfma_f32_16x16x32_bf16

// async global->LDS, 16B/lane. LDS dest = wave-uniform base + lane*16.
#define GLD_LDS16(gp, lp)                                                     \
    __builtin_amdgcn_global_load_lds(                                         \
        (const __attribute__((address_space(1))) void*)(gp),                  \
        (__attribute__((address_space(3))) void*)(lp), 16, 0, 0)

__device__ __forceinline__ u16 f2bf(float f) {
    unsigned int u = __builtin_bit_cast(unsigned int, f);
    u += 0x7FFFu + ((u >> 16) & 1u);
    return (u16)(u >> 16);
}
__device__ __forceinline__ float bf2f(u16 h) {
    unsigned int u = ((unsigned int)h) << 16;
    return __builtin_bit_cast(float, u);
}

// Unified fragment-contiguous swizzle for matrix M[R][K] (K = contraction):
//   flat = ((r>>4)*KT + (k>>5))*512 + (((k>>3)&3)*16 + (r&15))*8 + (k&7)
// One MFMA A/B fragment (rt, kt) = 1 KB contiguous at ((rt*KT+kt)*64+lane)*8.

// ---------------------------------------------------------------------------
// transpose_sw: X (b, c, n) fp32 -> X_sw (b, swizzle R=n K=c) bf16.
// grid (16, 6, 2*BATCH): z<32 -> rgb, z>=32 -> ms (one launch for both).
// ---------------------------------------------------------------------------
__global__ __launch_bounds__(256) void transpose_sw(
    const float* __restrict__ X0, u16* __restrict__ X0sw,
    const float* __restrict__ X1, u16* __restrict__ X1sw)
{
    __shared__ float tl[64 * 65];
    const int z = blockIdx.z;
    const float* X = (z < BATCH) ? X0 : X1;
    u16* Xsw = (z < BATCH) ? X0sw : X1sw;
    const int b = z & 31, n0 = blockIdx.x * 64, c0 = blockIdx.y * 64;
    const int t = threadIdx.x;

#pragma unroll
    for (int p = 0; p < 4; ++p) {
        int idx = p * 256 + t;
        int c = idx >> 4, n4 = (idx & 15) * 4;
        f32x4 v = *(const f32x4*)(X + ((size_t)b * DIMC + c0 + c) * NTOK + n0 + n4);
#pragma unroll
        for (int i = 0; i < 4; ++i) tl[c * 65 + n4 + i] = v[i];
    }
    __syncthreads();
    u16* dstb = Xsw + (size_t)b * NTOK * DIMC;
#pragma unroll
    for (int p = 0; p < 2; ++p) {
        int g = p * 256 + t;  // [3:0]=n15 [5:4]=quad [6]=ktl [8:7]=rg
        int n15 = g & 15, quad = (g >> 4) & 3, ktl = (g >> 6) & 1, rg = g >> 7;
        int c8 = ktl * 32 + quad * 8;
        int nl = rg * 16 + n15;
        uint4_ pk;
#pragma unroll
        for (int i = 0; i < 4; ++i) {
            u16 lo = f2bf(tl[(c8 + 2 * i) * 65 + nl]);
            u16 hi = f2bf(tl[(c8 + 2 * i + 1) * 65 + nl]);
            pk[i] = (unsigned)lo | ((unsigned)hi << 16);
        }
        size_t dst = (((size_t)(n0 >> 4) + rg) * KT12 + (c0 >> 5) + ktl) * 512 + (size_t)(g & 63) * 8;
        *(uint4_*)(dstb + dst) = pk;
    }
}

// ---------------------------------------------------------------------------
// wcvt_sw: 4 weight matrices (384x384 fp32 [d][c]) -> swizzle bf16 (R=d, K=c),
// concatenated. Matrix 0 (Wq) pre-scaled by scale*log2e. grid (72,4), 256 thr.
// ---------------------------------------------------------------------------
__global__ __launch_bounds__(256) void wcvt_sw(
    const float* __restrict__ w0, const float* __restrict__ w1,
    const float* __restrict__ w2, const float* __restrict__ w3,
    u16* __restrict__ dst, float s0)
{
    const float* srcs[4] = {w0, w1, w2, w3};
    const float* s = srcs[blockIdx.y];
    float scl = (blockIdx.y == 0) ? s0 : 1.0f;
    u16* d = dst + (size_t)blockIdx.y * DIMC * DIMC;
    int e0 = (blockIdx.x * 256 + threadIdx.x) * 8;
    int dd = e0 / DIMC, c8 = e0 % DIMC;
    f32x4 a = *(const f32x4*)(s + e0);
    f32x4 b2 = *(const f32x4*)(s + e0 + 4);
    uint4_ pk;
    pk[0] = (unsigned)f2bf(a[0] * scl) | ((unsigned)f2bf(a[1] * scl) << 16);
    pk[1] = (unsigned)f2bf(a[2] * scl) | ((unsigned)f2bf(a[3] * scl) << 16);
    pk[2] = (unsigned)f2bf(b2[0] * scl) | ((unsigned)f2bf(b2[1] * scl) << 16);
    pk[3] = (unsigned)f2bf(b2[2] * scl) | ((unsigned)f2bf(b2[3] * scl) << 16);
    size_t off = ((size_t)(dd >> 4) * KT12 + (c8 >> 5)) * 512 +
                 (size_t)((((c8 >> 3) & 3) * 16 + (dd & 15)) * 8);
    *(uint4_*)(d + off) = pk;
}

// ---------------------------------------------------------------------------
// proj3_g: q/k/v projections, staged GEMM (round-5 best-measured config).
// 128x128 tile, 4 waves (64x64 each, 64 AGPR), K-step 32 (12 steps), A+B
// double-buffered via global_load_lds, one __syncthreads per step. 32KB LDS
// (epilogue pw aliases staging) -> 4 blocks/CU of independent barrier
// domains (measured better than 3-block triple-buffer T4 variant).
// Grid 2304, 1-D: b = bid&31 -> batch XCD-local.
// ---------------------------------------------------------------------------
__global__ __launch_bounds__(256, 4) void proj3_g(
    const u16* __restrict__ rgb_sw, const u16* __restrict__ ms_sw,
    const u16* __restrict__ w_sw,
    u16* __restrict__ q_sw, u16* __restrict__ k_sw, u16* __restrict__ v_sw,
    const float* __restrict__ bq, const float* __restrict__ bk,
    const float* __restrict__ bv, float s0)
{
    // u16 layout: stA0 [0,4096) stA1 [4096,8192) stB0 [8192,12288)
    //             stB1 [12288,16384).  Epilogue pw (4x1216) aliases [0,4864).
    __shared__ __align__(16) u16 smem[16384];

    const int bid = blockIdx.x;
    const int b = bid & 31;
    const int rr = bid >> 5;              // [0,72)
    const int s = rr % 3, tile = rr / 3;  // tile in [0,24)
    const size_t TB = (size_t)NTOK * DIMC, WN = (size_t)DIMC * DIMC;
    const u16 *A, *B; u16* O; const float* bias;
    int ktd, bRow, r0, c0; float bsc = 1.f;
    if (s == 0) {
        A = rgb_sw + b * TB; B = w_sw; O = q_sw + b * TB; bias = bq;
        ktd = 12; bRow = 0; r0 = (tile & 7) * 128; c0 = (tile >> 3) * 128; bsc = s0;
    } else if (s == 1) {
        A = ms_sw + b * TB; B = w_sw + WN; O = k_sw + b * TB; bias = bk;
        ktd = 12; bRow = 0; r0 = (tile & 7) * 128; c0 = (tile >> 3) * 128;
    } else {
        A = w_sw + 2 * WN; B = ms_sw + b * TB; O = v_sw + b * TB; bias = bv;
        ktd = 32; bRow = 1; r0 = (tile % 3) * 128; c0 = (tile / 3) * 128;
    }

    const int t = threadIdx.x, w = t >> 6, lane = t & 63;
    const int l15 = lane & 15, quad = lane >> 4;
    const int wr = w >> 1, wc = w & 1;    // wave quadrant (rows, cols)
    const int rt0 = r0 >> 4, ct0 = c0 >> 4;

    f32x4 acc[4][4];
#pragma unroll
    for (int ai = 0; ai < 4; ++ai)
#pragma unroll
        for (int bj = 0; bj < 4; ++bj) acc[ai][bj] = (f32x4){0.f, 0.f, 0.f, 0.f};

    // prologue: stage K-step 0 into buffer 0 (wave w owns frags 2w, 2w+1)
    {
        const u16* As = A + ((size_t)(rt0 + 2 * w) * KT12) * 512 + (size_t)lane * 8;
        GLD_LDS16(As, smem + (2 * w) * 512);
        GLD_LDS16(As + KT12 * 512, smem + (2 * w + 1) * 512);
        const u16* Bs = B + ((size_t)(ct0 + 2 * w) * KT12) * 512 + (size_t)lane * 8;
        GLD_LDS16(Bs, smem + 8192 + (2 * w) * 512);
        GLD_LDS16(Bs + KT12 * 512, smem + 8192 + (2 * w + 1) * 512);
    }
    __syncthreads();

    for (int kt = 0; kt < 12; ++kt) {
        const int cur = kt & 1;
        if (kt < 11) {
            u16* dA = smem + (cur ^ 1) * 4096;
            u16* dB = smem + 8192 + (cur ^ 1) * 4096;
            const u16* As = A + ((size_t)(rt0 + 2 * w) * KT12 + kt + 1) * 512 + (size_t)lane * 8;
            GLD_LDS16(As, dA + (2 * w) * 512);
            GLD_LDS16(As + KT12 * 512, dA + (2 * w + 1) * 512);
            const u16* Bs = B + ((size_t)(ct0 + 2 * w) * KT12 + kt + 1) * 512 + (size_t)lane * 8;
            GLD_LDS16(Bs, dB + (2 * w) * 512);
            GLD_LDS16(Bs + KT12 * 512, dB + (2 * w + 1) * 512);
        }
        const u16* sA = smem + cur * 4096 + (size_t)(wr * 4) * 512 + (size_t)lane * 8;
        const u16* sB = smem + 8192 + cur * 4096 + (size_t)(wc * 4) * 512 + (size_t)lane * 8;
        short8 aF[4], bF[4];
#pragma unroll
        for (int ai = 0; ai < 4; ++ai) aF[ai] = *(const short8*)(sA + ai * 512);
#pragma unroll
        for (int bj = 0; bj < 4; ++bj) bF[bj] = *(const short8*)(sB + bj * 512);
        __builtin_amdgcn_s_setprio(1);
#pragma unroll
        for (int ai = 0; ai < 4; ++ai)
#pragma unroll
            for (int bj = 0; bj < 4; ++bj)
                acc[ai][bj] = MFMA16(aF[ai], bF[bj], acc[ai][bj], 0, 0, 0);
        __builtin_amdgcn_s_setprio(0);
        __syncthreads();  // drains vmcnt: next chunk landed; reads of cur done
    }
    // After the kt=11 barrier every wave's staging reads are complete ->
    // safe to alias pw onto the staging region.
    u16* pw = smem + w * 1216;

    // bias
    if (bRow) {
#pragma unroll
        for (int ai = 0; ai < 4; ++ai) {
            f32x4 bv4 = *(const f32x4*)(bias + r0 + wr * 64 + ai * 16 + quad * 4);
#pragma unroll
            for (int bj = 0; bj < 4; ++bj)
#pragma unroll
                for (int r = 0; r < 4; ++r) acc[ai][bj][r] += bv4[r];
        }
    } else {
#pragma unroll
        for (int bj = 0; bj < 4; ++bj) {
            float bc = bias[c0 + wc * 64 + bj * 16 + l15] * bsc;
#pragma unroll
            for (int ai = 0; ai < 4; ++ai)
#pragma unroll
                for (int r = 0; r < 4; ++r) acc[ai][bj][r] += bc;
        }
    }

    // epilogue: per-wave swizzled bf16 store (wave-private pw, no barriers)
#pragma unroll
    for (int ai = 0; ai < 4; ++ai) {
#pragma unroll
        for (int bj = 0; bj < 4; ++bj)
#pragma unroll
            for (int r = 0; r < 4; ++r)
                pw[(quad * 4 + r) * 76 + bj * 16 + l15] = f2bf(acc[ai][bj][r]);
        const int rt = rt0 + wr * 4 + ai;
        const int kb0 = (c0 + wc * 64) >> 5;
#pragma unroll
        for (int ktl = 0; ktl < 2; ++ktl) {
            uint4_ v = *(const uint4_*)(pw + l15 * 76 + ktl * 32 + quad * 8);
            *(uint4_*)(O + ((size_t)rt * ktd + kb0 + ktl) * 512 + (size_t)lane * 8) = v;
        }
    }
}

// ---------------------------------------------------------------------------
// projf_g: final projection, same round-5 staged-GEMM skeleton. 32KB LDS,
// __launch_bounds__(256,4). fp32 direct stores. grid 768.
// ---------------------------------------------------------------------------
__global__ __launch_bounds__(256, 4) void projf_g(
    const u16* __restrict__ wf_sw, const u16* __restrict__ osw,
    const float* __restrict__ bfp, float* __restrict__ out)
{
    __shared__ __align__(16) u16 smem[16384];
    const int bid = blockIdx.x;
    const int b = bid & 31, tile = bid >> 5;  // [0,24)
    const int r0 = (tile % 3) * 128, c0 = (tile / 3) * 128;
    const size_t TB = (size_t)NTOK * DIMC;

    const int t = threadIdx.x, w = t >> 6, lane = t & 63;
    const int l15 = lane & 15, quad = lane >> 4;
    const int wr = w >> 1, wc = w & 1;
    const int rt0 = r0 >> 4, ct0 = c0 >> 4;
    const u16* A = wf_sw;
    const u16* B = osw + (size_t)b * TB;

    f32x4 acc[4][4];
#pragma unroll
    for (int ai = 0; ai < 4; ++ai)
#pragma unroll
        for (int bj = 0; bj < 4; ++bj) acc[ai][bj] = (f32x4){0.f, 0.f, 0.f, 0.f};

    {
        const u16* As = A + ((size_t)(rt0 + 2 * w) * KT12) * 512 + (size_t)lane * 8;
        GLD_LDS16(As, smem + (2 * w) * 512);
        GLD_LDS16(As + KT12 * 512, smem + (2 * w + 1) * 512);
        const u16* Bs = B + ((size_t)(ct0 + 2 * w) * KT12) * 512 + (size_t)lane * 8;
        GLD_LDS16(Bs, smem + 8192 + (2 * w) * 512);
        GLD_LDS16(Bs + KT12 * 512, smem + 8192 + (2 * w + 1) * 512);
    }
    __syncthreads();

    for (int kt = 0; kt < 12; ++kt) {
        const int cur = kt & 1;
        if (kt < 11) {
            u16* dA = smem + (cur ^ 1) * 4096;
            u16* dB = smem + 8192 + (cur ^ 1) * 4096;
            const u16* As = A + ((size_t)(rt0 + 2 * w) * KT12 + kt + 1) * 512 + (size_t)lane * 8;
            GLD_LDS16(As, dA + (2 * w) * 512);
            GLD_LDS16(As + KT12 * 512, dA + (2 * w + 1) * 512);
            const u16* Bs = B + ((size_t)(ct0 + 2 * w) * KT12 + kt + 1) * 512 + (size_t)lane * 8;
            GLD_LDS16(Bs, dB + (2 * w) * 512);
            GLD_LDS16(Bs + KT12 * 512, dB + (2 * w + 1) * 512);
        }
        const u16* sA = smem + cur * 4096 + (size_t)(wr * 4) * 512 + (size_t)lane * 8;
        const u16* sB = smem + 8192 + cur * 4096 + (size_t)(wc * 4) * 512 + (size_t)lane * 8;
        short8 aF[4], bF[4];
#pragma unroll
        for (int ai = 0; ai < 4; ++ai) aF[ai] = *(const short8*)(sA + ai * 512);
#pragma unroll
        for (int bj = 0; bj < 4; ++bj) bF[bj] = *(const short8*)(sB + bj * 512);
        __builtin_amdgcn_s_setprio(1);
#pragma unroll
        for (int ai = 0; ai < 4; ++ai)
#pragma unroll
            for (int bj = 0; bj < 4; ++bj)
                acc[ai][bj] = MFMA16(aF[ai], bF[bj], acc[ai][bj], 0, 0, 0);
        __builtin_amdgcn_s_setprio(0);
        __syncthreads();
    }

    float* Ob = out + (size_t)b * DIMC * NTOK;
#pragma unroll
    for (int ai = 0; ai < 4; ++ai) {
        f32x4 bv4 = *(const f32x4*)(bfp + r0 + wr * 64 + ai * 16 + quad * 4);
#pragma unroll
        for (int bj = 0; bj < 4; ++bj) {
            const int col = c0 + wc * 64 + bj * 16 + l15;
#pragma unroll
            for (int r = 0; r < 4; ++r) {
                const int row = r0 + wr * 64 + ai * 16 + quad * 4 + r;
                Ob[(size_t)row * NTOK + col] = acc[ai][bj][r] + bv4[r];
            }
        }
    }
}

// ---------------------------------------------------------------------------
// attn_t4: flash attention, 128 q/block (8 waves x 16 q), 512 threads.
// Round-3 compute body, but the per-tile __syncthreads (full vmcnt(0) drain)
// is replaced by the T4 counted-vmcnt pattern: K TRIPLE-buffered, V double-
// buffered; per iter, issue V(t+1) then K(t+2); at iter top wait
// s_waitcnt vmcnt(3) -> drains exactly K(t)+V(t) (FIFO: [K(t),V(t),K(t+1)]
// outstanding), keeps K(t+1) in flight across the barrier. Tail: iter 30
// issues only V(31); iter 31 waits vmcnt(0). WAR: each buffer rewrite is
// separated from its last reader by the intervening barrier. sched_barrier(0)
// after s_barrier fences ds_read hoisting. LDS 139KB -> 1 block/CU (same
// occupancy/registers as the 105us version). Grid 256, batch-per-XCD mapping.
// ---------------------------------------------------------------------------
__global__ __launch_bounds__(512, 2) void attn_t4(
    const u16* __restrict__ qsw, const u16* __restrict__ ksw,
    const u16* __restrict__ vsw, u16* __restrict__ osw)
{
    // u16 layout: kbuf0/1/2 [0,36864)  vbuf0/1 [36864,61440)
    //             plds [61440,71168): 8 waves x 16 x 76
    __shared__ __align__(16) u16 smem[71168];

    const int bid = blockIdx.x;
    const int b = (bid & 7) * 4 + ((bid >> 3) & 3);  // same-batch blocks share XCD
    const int qb = bid >> 5;                         // [0,8): 128-q block index
    const int t = threadIdx.x, w = t >> 6, lane = t & 63;
    const int l15 = lane & 15, quad = lane >> 4;
    const int rt = qb * 8 + w;                       // global 16-q row-tile

    const size_t TB = (size_t)NTOK * DIMC;
    const u16* kb = ksw + (size_t)b * TB;
    const u16* vb = vsw + (size_t)b * TB;
    u16* pw = smem + 61440 + w * 1216;

    // Q fragments resident (pre-scaled by scale*log2e at projection)
    short8 qf[12];
    const u16* qp = qsw + (size_t)b * TB + (size_t)rt * (KT12 * 512) + (size_t)lane * 8;
#pragma unroll
    for (int dk = 0; dk < 12; ++dk) qf[dk] = *(const short8*)(qp + dk * 512);

    f32x4 Oa[24];
#pragma unroll
    for (int i = 0; i < 24; ++i) Oa[i] = (f32x4){0.f, 0.f, 0.f, 0.f};
    float m_run[4], l_run[4];
#pragma unroll
    for (int r = 0; r < 4; ++r) { m_run[r] = -1e30f; l_run[r] = 0.f; }

    const int i0 = w * 3;  // this wave's 3 fragment indices (of 24)

    // prologue DMA, FIFO order matters: V(0), K(0), K(1)
#pragma unroll
    for (int j = 0; j < 3; ++j) {
        int idx = i0 + j;
        GLD_LDS16(vb + (size_t)(idx * 32) * 512 + lane * 8, smem + 36864 + idx * 512);
    }
#pragma unroll
    for (int j = 0; j < 3; ++j) {
        int idx = i0 + j;
        GLD_LDS16(kb + (size_t)idx * 512 + lane * 8, smem + idx * 512);
    }
#pragma unroll
    for (int j = 0; j < 3; ++j) {
        int idx = i0 + j;
        GLD_LDS16(kb + (size_t)(24 + idx) * 512 + lane * 8, smem + 12288 + idx * 512);
    }

    for (int mt = 0; mt < 32; ++mt) {
        // counted wait: K(mt)+V(mt) landed; K(mt+1) may stay in flight
        if (mt < 31) {
            asm volatile("s_waitcnt vmcnt(3)" ::: "memory");
        } else {
            asm volatile("s_waitcnt vmcnt(0)" ::: "memory");
        }
        __builtin_amdgcn_s_barrier();
        __builtin_amdgcn_sched_barrier(0);

        // issue V(mt+1) then K(mt+2) (post-barrier: WAR-safe)
        if (mt < 31) {
            u16* vnxt = smem + 36864 + ((mt + 1) & 1) * 12288;
            const u16* vs = vb + (size_t)(mt + 1) * 512 + (size_t)lane * 8;
#pragma unroll
            for (int j = 0; j < 3; ++j) {
                int idx = i0 + j;
                GLD_LDS16(vs + (size_t)(idx * 32) * 512, vnxt + idx * 512);
            }
        }
        if (mt < 30) {
            u16* knxt = smem + ((mt + 2) % 3) * 12288;
            const u16* ks = kb + (size_t)(24 * (mt + 2)) * 512 + (size_t)lane * 8;
#pragma unroll
            for (int j = 0; j < 3; ++j) {
                int idx = i0 + j;
                GLD_LDS16(ks + (size_t)idx * 512, knxt + idx * 512);
            }
        }

        const u16* kcur = smem + (mt % 3) * 12288;
        const u16* vcur = smem + 36864 + (mt & 1) * 12288;

        // ---- QK: S[16 q][32 keys] from LDS K frags ----
        f32x4 s[2];
        s[0] = (f32x4){0.f, 0.f, 0.f, 0.f};
        s[1] = (f32x4){0.f, 0.f, 0.f, 0.f};
        const u16* kfb = kcur + (size_t)lane * 8;
        __builtin_amdgcn_s_setprio(1);
#pragma unroll
        for (int dk = 0; dk < 12; ++dk) {
            short8 k0 = *(const short8*)(kfb + dk * 512);
            short8 k1 = *(const short8*)(kfb + (12 + dk) * 512);
            s[0] = MFMA16(qf[dk], k0, s[0], 0, 0, 0);
            s[1] = MFMA16(qf[dk], k1, s[1], 0, 0, 0);
        }
        __builtin_amdgcn_s_setprio(0);

        // ---- online softmax (log2-domain, deferred-max THR=8) ----
        float mx4[4];
#pragma unroll
        for (int r = 0; r < 4; ++r) {
            float mx = fmaxf(s[0][r], s[1][r]);
            mx = fmaxf(mx, __shfl_xor(mx, 1));
            mx = fmaxf(mx, __shfl_xor(mx, 2));
            mx = fmaxf(mx, __shfl_xor(mx, 4));
            mx = fmaxf(mx, __shfl_xor(mx, 8));
            mx4[r] = mx;
        }
        int grow = (mx4[0] > m_run[0] + 8.f) | (mx4[1] > m_run[1] + 8.f) |
                   (mx4[2] > m_run[2] + 8.f) | (mx4[3] > m_run[3] + 8.f);
        if (__any(grow)) {
            float alpha[4];
#pragma unroll
            for (int r = 0; r < 4; ++r) {
                float mn = fmaxf(m_run[r], mx4[r]);
                alpha[r] = exp2f(m_run[r] - mn);
                m_run[r] = mn;
                l_run[r] *= alpha[r];
            }
#pragma unroll
            for (int ci = 0; ci < 24; ++ci)
#pragma unroll
                for (int r = 0; r < 4; ++r) Oa[ci][r] *= alpha[r];
        }
#pragma unroll
        for (int r = 0; r < 4; ++r) {
            float ls = 0.f;
#pragma unroll
            for (int mc = 0; mc < 2; ++mc) {
                float p = exp2f(s[mc][r] - m_run[r]);
                u16 pb = f2bf(p);
                pw[(quad * 4 + r) * 76 + mc * 16 + l15] = pb;
                ls += bf2f(pb);  // denominator from rounded P -> exact normalization
            }
            ls += __shfl_xor(ls, 1);
            ls += __shfl_xor(ls, 2);
            ls += __shfl_xor(ls, 4);
            ls += __shfl_xor(ls, 8);
            l_run[r] += ls;
        }

        // ---- PV: P (wave-private LDS) x V (LDS), 24 independent chains ----
        short8 pa = *(const short8*)(pw + l15 * 76 + quad * 8);
        const u16* vfb = vcur + (size_t)lane * 8;
        __builtin_amdgcn_s_setprio(1);
#pragma unroll
        for (int ci = 0; ci < 24; ++ci) {
            short8 vf = *(const short8*)(vfb + ci * 512);
            Oa[ci] = MFMA16(pa, vf, Oa[ci], 0, 0, 0);
        }
        __builtin_amdgcn_s_setprio(0);
        // no trailing barrier: next iteration's {vmcnt wait; s_barrier} covers
        // both the RAW (DMA landed) and WAR (reads done) hazards.
    }

    // ---- epilogue: normalize + wave-private transpose via pw + store ----
    float rl[4];
#pragma unroll
    for (int r = 0; r < 4; ++r) rl[r] = 1.f / l_run[r];
    u16* od = osw + (size_t)b * TB;
#pragma unroll
    for (int ch = 0; ch < 6; ++ch) {
#pragma unroll
        for (int cc = 0; cc < 4; ++cc)
#pragma unroll
            for (int r = 0; r < 4; ++r)
                pw[(quad * 4 + r) * 76 + cc * 16 + l15] = f2bf(Oa[ch * 4 + cc][r] * rl[r]);
#pragma unroll
        for (int ktl = 0; ktl < 2; ++ktl) {
            uint4_ vv = *(const uint4_*)(pw + l15 * 76 + ktl * 32 + quad * 8);
            size_t dst = ((size_t)rt * KT12 + ch * 2 + ktl) * 512 + (size_t)lane * 8;
            *(uint4_*)(od + dst) = vv;
        }
    }
}

extern "C" void kernel_launch(void* const* d_in, const int* in_sizes, int n_in,
                              void* d_out, int out_size, void* d_ws, size_t ws_size,
                              hipStream_t stream) {
    const float* rgb = (const float*)d_in[0];
    const float* ms  = (const float*)d_in[1];
    const float* Wq  = (const float*)d_in[2];
    const float* bq  = (const float*)d_in[3];
    const float* Wk  = (const float*)d_in[4];
    const float* bk  = (const float*)d_in[5];
    const float* Wv  = (const float*)d_in[6];
    const float* bv  = (const float*)d_in[7];
    const float* Wf  = (const float*)d_in[8];
    const float* bf_ = (const float*)d_in[9];
    float* outp = (float*)d_out;

    const float SC2 = 0.05103103630798288f * 1.4426950408889634f;  // scale*log2e

    const size_t TN = (size_t)BATCH * NTOK * DIMC;  // 12.58M elems
    const size_t WN = (size_t)DIMC * DIMC;          // 147456
    u16* rgb_sw = (u16*)d_ws;         // swizzle R=n K=c
    u16* ms_sw  = rgb_sw + TN;
    u16* q_sw   = ms_sw + TN;         // R=n K=d (pre-scaled)
    u16* k_sw   = q_sw + TN;          // R=m K=d
    u16* v_sw   = k_sw + TN;          // R=c K=m (KT=32)
    u16* o_sw   = v_sw + TN;          // R=n K=c
    u16* w_sw   = o_sw + TN;          // Wq,Wk,Wv,Wf swizzled concat
    // total ws: 6*25.2MB + 1.2MB = 152 MB

    wcvt_sw<<<dim3(72, 4), 256, 0, stream>>>(Wq, Wk, Wv, Wf, w_sw, SC2);
    transpose_sw<<<dim3(16, 6, 2 * BATCH), 256, 0, stream>>>(rgb, rgb_sw, ms, ms_sw);

    proj3_g<<<dim3(2304), 256, 0, stream>>>(
        rgb_sw, ms_sw, w_sw, q_sw, k_sw, v_sw, bq, bk, bv, SC2);

    attn_t4<<<dim3(256), 512, 0, stream>>>(q_sw, k_sw, v_sw, o_sw);

    projf_g<<<dim3(768), 256, 0, stream>>>(w_sw + 3 * WN, o_sw, bf_, outp);
}